// Round 4
// baseline (380.823 us; speedup 1.0000x reference)
//
#include <hip/hip_runtime.h>

// Problem constants
#define NB 2        // batch
#define NPTS 1024   // points per cloud
#define NGEN 65536  // G * D_IN generated points per batch

// ws layout (float offsets), all 16B-aligned where accessed as float4.
#define OFF_H1PRE 0        // 1024
#define OFF_ZW    1280     // 256
#define OFF_GW    1536     // 8192
#define OFF_D2H   9728     // 65536
#define OFF_S4    75264    // 8192
#define OFF_Y4    83456    // 524288
#define OFF_WT4   607744   // 1572864 (3*128*1024 float4)
#define OFF_MP1   2180608  // 262144 (dir1 partial mins: [b][mh][65536])
#define OFF_MP2   2442752  // 262144 (dir2 partial mins: [b][nch][h][1024])
// total 2704896 floats = 10.8 MB

// ---------------- K0: init + S4 + gw + Wd3 transpose + encoder L1 ----------
// blocks 0..63: init; 64..1599: transpose Wd3 -> Wt4[c][k4][p];
// 1600..1603: encoder L1 full-K dots (no atomics, h1pre = x @ We1 raw).
__global__ __launch_bounds__(256) void k0_mega(
    const float* __restrict__ x, const float* __restrict__ grid,
    const float* __restrict__ Wd1, const float* __restrict__ Wd3,
    const float* __restrict__ We1,
    float* __restrict__ gw, float* __restrict__ S4,
    float4* __restrict__ Wt4, float* __restrict__ h1pre,
    float* __restrict__ out) {
  int blk = blockIdx.x;
  if (blk < 64) {
    int t = blk * 256 + threadIdx.x;
    if (t < 8192) {
      int g = t >> 7, j = t & 127;
      float a = grid[g * 3 + 0] * Wd1[64 * 128 + j]
              + grid[g * 3 + 1] * Wd1[65 * 128 + j]
              + grid[g * 3 + 2] * Wd1[66 * 128 + j];
      gw[t] = a;
    } else if (t < 10240) {
      int p = t - 8192;
      const float* xp = x + p * 3;
      float s0 = xp[0], s1 = xp[1], s2 = xp[2];
      ((float4*)S4)[p] = make_float4(s0, s1, s2, s0 * s0 + s1 * s1 + s2 * s2);
    } else if (t == 10240) {
      out[0] = 0.f;
    }
  } else if (blk < 1600) {
    int tid = (blk - 64) * 256 + threadIdx.x;         // 0..393215
    int p  = tid & 1023;
    int k4 = (tid >> 10) & 127;
    int c  = tid >> 17;                               // 0..2
    const float* W = Wd3 + (k4 * 4) * 3072 + p * 3 + c;
    float w0 = W[0], w1 = W[3072], w2 = W[2 * 3072], w3 = W[3 * 3072];
    Wt4[(c * 128 + k4) * 1024 + p] = make_float4(w0, w1, w2, w3);
  } else {
    // encoder L1: 4 blocks x 256 threads = 1024 = (b, j)
    int bj = (blk - 1600) * 256 + threadIdx.x;        // 0..1023
    int b = bj >> 9, j = bj & 511;
    const float* xb = x + b * 3072;                   // uniform -> s_load
    const float* W = We1 + j;
    float acc = 0.f;
#pragma unroll 8
    for (int k = 0; k < 3072; ++k) acc += xb[k] * W[k * 512];
    h1pre[bj] = acc;                                  // raw (bias in k23)
  }
}

// ---------------- K23: encoder L2 + L3 + zw, single block ----------------
__global__ __launch_bounds__(256) void k23_enc(
    const float* __restrict__ h1pre, const float* __restrict__ be1,
    const float* __restrict__ We2, const float* __restrict__ be2,
    const float* __restrict__ We3, const float* __restrict__ be3,
    const float* __restrict__ Wd1, const float* __restrict__ bd1,
    float* __restrict__ zw) {
  __shared__ float h1s[1024];
  __shared__ float h2s[256];
  __shared__ float zs[128];
  int t = threadIdx.x;
#pragma unroll
  for (int o = 0; o < 4; ++o) {
    int idx = o * 256 + t;
    h1s[idx] = fmaxf(h1pre[idx] + be1[idx & 511], 0.f);
  }
  __syncthreads();
  {
    int b = t >> 7, j = t & 127;
    float acc = be2[j];
#pragma unroll 4
    for (int k = 0; k < 512; ++k) acc += h1s[b * 512 + k] * We2[k * 128 + j];
    h2s[t] = fmaxf(acc, 0.f);
  }
  __syncthreads();
  if (t < 128) {
    int b = t >> 6, j = t & 63;
    float acc = be3[j];
#pragma unroll 4
    for (int k = 0; k < 128; ++k) acc += h2s[b * 128 + k] * We3[k * 64 + j];
    zs[t] = fmaxf(acc, 0.f);
  }
  __syncthreads();
  {
    int b = t >> 7, jj = t & 127;
    float a2 = bd1[jj];
#pragma unroll 4
    for (int k = 0; k < 64; ++k) a2 += zs[b * 64 + k] * Wd1[k * 128 + jj];
    zw[t] = a2;                          // relu applied with gw in k4
  }
}

// ---------------- K4: decoder L2 ----------------
__global__ __launch_bounds__(256) void k4_dec2(
    const float* __restrict__ zw, const float* __restrict__ gw,
    const float* __restrict__ Wd2, const float* __restrict__ bd2,
    float* __restrict__ d2h) {
  __shared__ float d1[128];
  int bg = blockIdx.x;
  int b = bg >> 6, g = bg & 63;
  int t = threadIdx.x;
  if (t < 128) d1[t] = fmaxf(zw[b * 128 + t] + gw[g * 128 + t], 0.f);
  __syncthreads();
  float a0 = bd2[t], a1 = bd2[t + 256];
#pragma unroll 4
  for (int k = 0; k < 128; ++k) {
    float dv = d1[k];
    a0 += dv * Wd2[k * 512 + t];
    a1 += dv * Wd2[k * 512 + t + 256];
  }
  float* o = d2h + bg * 512;
  o[t] = fmaxf(a0, 0.f);
  o[t + 256] = fmaxf(a1, 0.f);
}

// ---------------- K5: decoder L3 + tanh + (-2y, |y|^2) pack ----------------
// 256 blocks = rt(16 row-tiles of 8) x pg(16); 256 threads (4 waves).
__global__ __launch_bounds__(256) void k5_dec3_y4(
    const float* __restrict__ d2h, const float4* __restrict__ Wt4,
    const float* __restrict__ bd3, float4* __restrict__ Y4) {
  __shared__ float4 a_lds[8 * 128];        // 8 rows x 512 k = 16 KB
  int rt = blockIdx.x >> 4;
  int pg = blockIdx.x & 15;
  int t = threadIdx.x;
  {
    const float4* src = (const float4*)d2h + rt * 1024;
#pragma unroll
    for (int i = 0; i < 4; ++i) a_lds[i * 256 + t] = src[i * 256 + t];
  }
  __syncthreads();
  int lane = t & 63, w = t >> 6;
  int r0 = w * 2, r1 = w * 2 + 1;
  int p = pg * 64 + lane;
  const float4* wp0 = Wt4 + p;             // c=0
  const float4* wp1 = Wt4 + 131072 + p;    // c=1
  const float4* wp2 = Wt4 + 262144 + p;    // c=2
  float a00 = 0.f, a01 = 0.f, a02 = 0.f;
  float a10 = 0.f, a11 = 0.f, a12 = 0.f;
#pragma unroll 4
  for (int k4 = 0; k4 < 128; ++k4) {
    float4 A0 = a_lds[r0 * 128 + k4];      // wave-uniform broadcast
    float4 A1 = a_lds[r1 * 128 + k4];
    float4 w0 = wp0[k4 * 1024];
    float4 w1 = wp1[k4 * 1024];
    float4 w2 = wp2[k4 * 1024];
    a00 += A0.x * w0.x + A0.y * w0.y + A0.z * w0.z + A0.w * w0.w;
    a01 += A0.x * w1.x + A0.y * w1.y + A0.z * w1.z + A0.w * w1.w;
    a02 += A0.x * w2.x + A0.y * w2.y + A0.z * w2.z + A0.w * w2.w;
    a10 += A1.x * w0.x + A1.y * w0.y + A1.z * w0.z + A1.w * w0.w;
    a11 += A1.x * w1.x + A1.y * w1.y + A1.z * w1.z + A1.w * w1.w;
    a12 += A1.x * w2.x + A1.y * w2.y + A1.z * w2.z + A1.w * w2.w;
  }
  float b0 = bd3[p * 3], b1 = bd3[p * 3 + 1], b2 = bd3[p * 3 + 2];
  {
    int row = rt * 8 + r0;
    float y0 = tanhf(a00 + b0), y1 = tanhf(a01 + b1), y2 = tanhf(a02 + b2);
    Y4[row * 1024 + p] = make_float4(-2.f * y0, -2.f * y1, -2.f * y2,
                                     y0 * y0 + y1 * y1 + y2 * y2);
  }
  {
    int row = rt * 8 + r1;
    float y0 = tanhf(a10 + b0), y1 = tanhf(a11 + b1), y2 = tanhf(a12 + b2);
    Y4[row * 1024 + p] = make_float4(-2.f * y0, -2.f * y1, -2.f * y2,
                                     y0 * y0 + y1 * y1 + y2 * y2);
  }
}

// ---------------- K67: chamfer, 8 resident points/thread ----------------
// blocks 0..127: dir1 = (b, nt 0..31, mh 0..1): 2048 resident y, 512 s in LDS.
// blocks 128..255: dir2 = (b, nch 0..63): 1024 y in LDS, 8 s/thread,
//   half-block h covers 512 of the chunk's n.
// 256 blocks = 1/CU; inner loop: 1 ds_read_b128 + 32 VALU (VALU-bound).
__global__ __launch_bounds__(256) void k67_chamfer(
    const float4* __restrict__ Y4, const float4* __restrict__ S4,
    float* __restrict__ mp1, float* __restrict__ mp2) {
  int t = threadIdx.x;
  if (blockIdx.x < 128) {
    // ---- dir1 ----
    int b  = blockIdx.x >> 6;
    int nt = (blockIdx.x >> 1) & 31;
    int mh = blockIdx.x & 1;
    __shared__ float4 s_lds[512];          // 8 KB
    {
      const float4* src = S4 + b * 1024 + mh * 512;
      s_lds[t] = src[t];
      s_lds[256 + t] = src[256 + t];
    }
    const float4* yp = Y4 + b * 65536 + nt * 2048;
    float4 y0 = yp[0 * 256 + t], y1 = yp[1 * 256 + t];
    float4 y2 = yp[2 * 256 + t], y3 = yp[3 * 256 + t];
    float4 y4 = yp[4 * 256 + t], y5 = yp[5 * 256 + t];
    float4 y6 = yp[6 * 256 + t], y7 = yp[7 * 256 + t];
    __syncthreads();
    float mn0 = __builtin_inff(), mn1 = mn0, mn2 = mn0, mn3 = mn0;
    float mn4 = mn0, mn5 = mn0, mn6 = mn0, mn7 = mn0;
#pragma unroll 4
    for (int m = 0; m < 512; ++m) {
      float4 s = s_lds[m];                 // block-uniform broadcast
      mn0 = fminf(mn0, __builtin_fmaf(s.x, y0.x, __builtin_fmaf(s.y, y0.y, __builtin_fmaf(s.z, y0.z, s.w))));
      mn1 = fminf(mn1, __builtin_fmaf(s.x, y1.x, __builtin_fmaf(s.y, y1.y, __builtin_fmaf(s.z, y1.z, s.w))));
      mn2 = fminf(mn2, __builtin_fmaf(s.x, y2.x, __builtin_fmaf(s.y, y2.y, __builtin_fmaf(s.z, y2.z, s.w))));
      mn3 = fminf(mn3, __builtin_fmaf(s.x, y3.x, __builtin_fmaf(s.y, y3.y, __builtin_fmaf(s.z, y3.z, s.w))));
      mn4 = fminf(mn4, __builtin_fmaf(s.x, y4.x, __builtin_fmaf(s.y, y4.y, __builtin_fmaf(s.z, y4.z, s.w))));
      mn5 = fminf(mn5, __builtin_fmaf(s.x, y5.x, __builtin_fmaf(s.y, y5.y, __builtin_fmaf(s.z, y5.z, s.w))));
      mn6 = fminf(mn6, __builtin_fmaf(s.x, y6.x, __builtin_fmaf(s.y, y6.y, __builtin_fmaf(s.z, y6.z, s.w))));
      mn7 = fminf(mn7, __builtin_fmaf(s.x, y7.x, __builtin_fmaf(s.y, y7.y, __builtin_fmaf(s.z, y7.z, s.w))));
    }
    float* dst = mp1 + (b * 2 + mh) * 65536 + nt * 2048;
    dst[0 * 256 + t] = mn0 + y0.w;
    dst[1 * 256 + t] = mn1 + y1.w;
    dst[2 * 256 + t] = mn2 + y2.w;
    dst[3 * 256 + t] = mn3 + y3.w;
    dst[4 * 256 + t] = mn4 + y4.w;
    dst[5 * 256 + t] = mn5 + y5.w;
    dst[6 * 256 + t] = mn6 + y6.w;
    dst[7 * 256 + t] = mn7 + y7.w;
  } else {
    // ---- dir2 ----
    int blk = blockIdx.x - 128;
    int b = blk >> 6, nch = blk & 63;
    __shared__ float4 y_lds[1024];         // 16 KB
    {
      const float4* src = Y4 + b * 65536 + nch * 1024;
#pragma unroll
      for (int i = 0; i < 4; ++i) y_lds[i * 256 + t] = src[i * 256 + t];
    }
    int h = t >> 7, tm = t & 127;
    const float4* sp = S4 + b * 1024;
    float4 s0 = sp[0 * 128 + tm], s1 = sp[1 * 128 + tm];
    float4 s2 = sp[2 * 128 + tm], s3 = sp[3 * 128 + tm];
    float4 s4 = sp[4 * 128 + tm], s5 = sp[5 * 128 + tm];
    float4 s6 = sp[6 * 128 + tm], s7 = sp[7 * 128 + tm];
    __syncthreads();
    float mn0 = __builtin_inff(), mn1 = mn0, mn2 = mn0, mn3 = mn0;
    float mn4 = mn0, mn5 = mn0, mn6 = mn0, mn7 = mn0;
    const float4* yq = y_lds + h * 512;
#pragma unroll 4
    for (int nn = 0; nn < 512; ++nn) {
      float4 y = yq[nn];                   // wave-uniform broadcast
      mn0 = fminf(mn0, __builtin_fmaf(y.x, s0.x, __builtin_fmaf(y.y, s0.y, __builtin_fmaf(y.z, s0.z, y.w))));
      mn1 = fminf(mn1, __builtin_fmaf(y.x, s1.x, __builtin_fmaf(y.y, s1.y, __builtin_fmaf(y.z, s1.z, y.w))));
      mn2 = fminf(mn2, __builtin_fmaf(y.x, s2.x, __builtin_fmaf(y.y, s2.y, __builtin_fmaf(y.z, s2.z, y.w))));
      mn3 = fminf(mn3, __builtin_fmaf(y.x, s3.x, __builtin_fmaf(y.y, s3.y, __builtin_fmaf(y.z, s3.z, y.w))));
      mn4 = fminf(mn4, __builtin_fmaf(y.x, s4.x, __builtin_fmaf(y.y, s4.y, __builtin_fmaf(y.z, s4.z, y.w))));
      mn5 = fminf(mn5, __builtin_fmaf(y.x, s5.x, __builtin_fmaf(y.y, s5.y, __builtin_fmaf(y.z, s5.z, y.w))));
      mn6 = fminf(mn6, __builtin_fmaf(y.x, s6.x, __builtin_fmaf(y.y, s6.y, __builtin_fmaf(y.z, s6.z, y.w))));
      mn7 = fminf(mn7, __builtin_fmaf(y.x, s7.x, __builtin_fmaf(y.y, s7.y, __builtin_fmaf(y.z, s7.z, y.w))));
    }
    float* dst = mp2 + ((b * 64 + nch) * 2 + h) * 1024;
    dst[0 * 128 + tm] = mn0 + s0.w;
    dst[1 * 128 + tm] = mn1 + s1.w;
    dst[2 * 128 + tm] = mn2 + s2.w;
    dst[3 * 128 + tm] = mn3 + s3.w;
    dst[4 * 128 + tm] = mn4 + s4.w;
    dst[5 * 128 + tm] = mn5 + s5.w;
    dst[6 * 128 + tm] = mn6 + s6.w;
    dst[7 * 128 + tm] = mn7 + s7.w;
  }
}

// ---------------- K8: final reduce (both directions) ----------------
// blocks 0..63: dir1 (min over 2 m-halves, sum). blocks 64..71: dir2
// (min over 128 chunk-slots per (b,m), sum). One atomicAdd per block.
__global__ __launch_bounds__(256) void k8_reduce(
    const float* __restrict__ mp1, const float* __restrict__ mp2,
    float* __restrict__ out) {
  int t = threadIdx.x;
  float v = 0.f;
  if (blockIdx.x < 64) {
    int base = blockIdx.x * 2048;
#pragma unroll
    for (int i = 0; i < 8; ++i) {
      int n = base + i * 256 + t;          // 0..131071 = b*65536 + nn
      int b = n >> 16, nn = n & 65535;
      v += fminf(mp1[b * 131072 + nn], mp1[b * 131072 + 65536 + nn]);
    }
  } else {
    int gid = (blockIdx.x - 64) * 256 + t; // 0..2047 = (b, m)
    int b = gid >> 10, m = gid & 1023;
    float mv = __builtin_inff();
#pragma unroll 8
    for (int ch = 0; ch < 128; ++ch)
      mv = fminf(mv, mp2[(b * 128 + ch) * 1024 + m]);  // coalesced over m
    v = mv;
  }
#pragma unroll
  for (int off = 32; off > 0; off >>= 1) v += __shfl_down(v, off);
  __shared__ float bsum[4];
  int lane = t & 63, w = t >> 6;
  if (lane == 0) bsum[w] = v;
  __syncthreads();
  if (t == 0) atomicAdd(out, bsum[0] + bsum[1] + bsum[2] + bsum[3]);
}

extern "C" void kernel_launch(void* const* d_in, const int* in_sizes, int n_in,
                              void* d_out, int out_size, void* d_ws, size_t ws_size,
                              hipStream_t stream) {
  const float* x   = (const float*)d_in[0];
  const float* grd = (const float*)d_in[1];
  const float* We1 = (const float*)d_in[2];
  const float* be1 = (const float*)d_in[3];
  const float* We2 = (const float*)d_in[4];
  const float* be2 = (const float*)d_in[5];
  const float* We3 = (const float*)d_in[6];
  const float* be3 = (const float*)d_in[7];
  const float* Wd1 = (const float*)d_in[8];
  const float* bd1 = (const float*)d_in[9];
  const float* Wd2 = (const float*)d_in[10];
  const float* bd2 = (const float*)d_in[11];
  const float* Wd3 = (const float*)d_in[12];
  const float* bd3 = (const float*)d_in[13];
  float* ws = (float*)d_ws;
  float* out = (float*)d_out;

  float* h1pre = ws + OFF_H1PRE;
  float* zw    = ws + OFF_ZW;
  float* gw    = ws + OFF_GW;
  float* d2h   = ws + OFF_D2H;
  float* S4    = ws + OFF_S4;
  float* Y4    = ws + OFF_Y4;
  float4* Wt4  = (float4*)(ws + OFF_WT4);
  float* mp1   = ws + OFF_MP1;
  float* mp2   = ws + OFF_MP2;

  hipLaunchKernelGGL(k0_mega, dim3(1604), dim3(256), 0, stream,
                     x, grd, Wd1, Wd3, We1, gw, S4, Wt4, h1pre, out);
  hipLaunchKernelGGL(k23_enc, dim3(1), dim3(256), 0, stream,
                     h1pre, be1, We2, be2, We3, be3, Wd1, bd1, zw);
  hipLaunchKernelGGL(k4_dec2, dim3(128), dim3(256), 0, stream,
                     zw, gw, Wd2, bd2, d2h);
  hipLaunchKernelGGL(k5_dec3_y4, dim3(256), dim3(256), 0, stream,
                     d2h, Wt4, bd3, (float4*)Y4);
  hipLaunchKernelGGL(k67_chamfer, dim3(256), dim3(256), 0, stream,
                     (const float4*)Y4, (const float4*)S4, mp1, mp2);
  hipLaunchKernelGGL(k8_reduce, dim3(72), dim3(256), 0, stream,
                     mp1, mp2, out);
}

// Round 5
// 241.247 us; speedup vs baseline: 1.5786x; 1.5786x over previous
//
#include <hip/hip_runtime.h>

// Problem constants
#define NB 2        // batch
#define NPTS 1024   // points per cloud
#define NGEN 65536  // G * D_IN generated points per batch

// ws layout (float offsets), all 16B-aligned where accessed as float4.
#define OFF_H1PRE 0        // 1024
#define OFF_ZW    1280     // 256
#define OFF_GW    1536     // 8192
#define OFF_D2H   9728     // 65536
#define OFF_S4    75264    // 8192
#define OFF_Y4    83456    // 524288
#define OFF_WT4   607744   // 1572864 (3*128*1024 float4)
#define OFF_MP1   2180608  // 262144 (dir1 partial mins: [b][mh][65536])
#define OFF_MP2   2442752  // 262144 (dir2 partial mins: [b][nch][h][1024])
// total 2704896 floats = 10.8 MB

// ---------------- K0: init + S4 + gw + h1pre zero + Wd3 transpose ----------
// blocks 0..63: init; 64..1599: transpose Wd3 -> Wt4[c][k4][p]
__global__ __launch_bounds__(256) void k0_init_t(
    const float* __restrict__ x, const float* __restrict__ grid,
    const float* __restrict__ Wd1, const float* __restrict__ Wd3,
    float* __restrict__ gw, float* __restrict__ S4,
    float4* __restrict__ Wt4, float* __restrict__ h1pre,
    float* __restrict__ out) {
  int blk = blockIdx.x;
  if (blk < 64) {
    int t = blk * 256 + threadIdx.x;
    if (t < 8192) {
      int g = t >> 7, j = t & 127;
      float a = grid[g * 3 + 0] * Wd1[64 * 128 + j]
              + grid[g * 3 + 1] * Wd1[65 * 128 + j]
              + grid[g * 3 + 2] * Wd1[66 * 128 + j];
      gw[t] = a;
    } else if (t < 10240) {
      int p = t - 8192;
      const float* xp = x + p * 3;
      float s0 = xp[0], s1 = xp[1], s2 = xp[2];
      ((float4*)S4)[p] = make_float4(s0, s1, s2, s0 * s0 + s1 * s1 + s2 * s2);
    } else if (t < 11264) {
      h1pre[t - 10240] = 0.f;
    } else if (t == 11264) {
      out[0] = 0.f;
    }
  } else {
    int tid = (blk - 64) * 256 + threadIdx.x;         // 0..393215
    int p  = tid & 1023;
    int k4 = (tid >> 10) & 127;
    int c  = tid >> 17;                               // 0..2
    const float* W = Wd3 + (k4 * 4) * 3072 + p * 3 + c;
    float w0 = W[0], w1 = W[3072], w2 = W[2 * 3072], w3 = W[3 * 3072];
    Wt4[(c * 128 + k4) * 1024 + p] = make_float4(w0, w1, w2, w3);
  }
}

// ---------------- K1: encoder L1 partial sums (k-split, proven R2) --------
// grid 192 = b(2) x jb(4) x kc(24); 128 threads; h1pre = raw x @ We1.
__global__ __launch_bounds__(128) void k1_enc1(
    const float* __restrict__ x, const float* __restrict__ We1,
    float* __restrict__ h1pre) {
  int blk = blockIdx.x;
  int kc = blk % 24;
  int jb = (blk / 24) % 4;
  int b  = blk / 96;
  int j = jb * 128 + threadIdx.x;
  const float* xb = x + b * 3072 + kc * 128;   // uniform -> s_load
  const float* W  = We1 + (kc * 128) * 512 + j;
  float acc = 0.f;
#pragma unroll 8
  for (int k = 0; k < 128; ++k) acc += xb[k] * W[k * 512];
  atomicAdd(&h1pre[b * 512 + j], acc);
}

// ---------------- K23: encoder L2 + L3 + zw, single block ----------------
__global__ __launch_bounds__(256) void k23_enc(
    const float* __restrict__ h1pre, const float* __restrict__ be1,
    const float* __restrict__ We2, const float* __restrict__ be2,
    const float* __restrict__ We3, const float* __restrict__ be3,
    const float* __restrict__ Wd1, const float* __restrict__ bd1,
    float* __restrict__ zw) {
  __shared__ float h1s[1024];
  __shared__ float h2s[256];
  __shared__ float zs[128];
  int t = threadIdx.x;
#pragma unroll
  for (int o = 0; o < 4; ++o) {
    int idx = o * 256 + t;
    h1s[idx] = fmaxf(h1pre[idx] + be1[idx & 511], 0.f);
  }
  __syncthreads();
  {
    int b = t >> 7, j = t & 127;
    float acc = be2[j];
#pragma unroll 4
    for (int k = 0; k < 512; ++k) acc += h1s[b * 512 + k] * We2[k * 128 + j];
    h2s[t] = fmaxf(acc, 0.f);
  }
  __syncthreads();
  if (t < 128) {
    int b = t >> 6, j = t & 63;
    float acc = be3[j];
#pragma unroll 4
    for (int k = 0; k < 128; ++k) acc += h2s[b * 128 + k] * We3[k * 64 + j];
    zs[t] = fmaxf(acc, 0.f);
  }
  __syncthreads();
  {
    int b = t >> 7, jj = t & 127;
    float a2 = bd1[jj];
#pragma unroll 4
    for (int k = 0; k < 64; ++k) a2 += zs[b * 64 + k] * Wd1[k * 128 + jj];
    zw[t] = a2;                          // relu applied with gw in k4
  }
}

// ---------------- K4: decoder L2 ----------------
__global__ __launch_bounds__(256) void k4_dec2(
    const float* __restrict__ zw, const float* __restrict__ gw,
    const float* __restrict__ Wd2, const float* __restrict__ bd2,
    float* __restrict__ d2h) {
  __shared__ float d1[128];
  int bg = blockIdx.x;
  int b = bg >> 6, g = bg & 63;
  int t = threadIdx.x;
  if (t < 128) d1[t] = fmaxf(zw[b * 128 + t] + gw[g * 128 + t], 0.f);
  __syncthreads();
  float a0 = bd2[t], a1 = bd2[t + 256];
#pragma unroll 4
  for (int k = 0; k < 128; ++k) {
    float dv = d1[k];
    a0 += dv * Wd2[k * 512 + t];
    a1 += dv * Wd2[k * 512 + t + 256];
  }
  float* o = d2h + bg * 512;
  o[t] = fmaxf(a0, 0.f);
  o[t + 256] = fmaxf(a1, 0.f);
}

// ---------------- K5: decoder L3 + tanh + (-2y, |y|^2) pack ----------------
// 256 blocks = rt(16 row-tiles of 8) x pg(16); 256 threads (4 waves).
__global__ __launch_bounds__(256) void k5_dec3_y4(
    const float* __restrict__ d2h, const float4* __restrict__ Wt4,
    const float* __restrict__ bd3, float4* __restrict__ Y4) {
  __shared__ float4 a_lds[8 * 128];        // 8 rows x 512 k = 16 KB
  int rt = blockIdx.x >> 4;
  int pg = blockIdx.x & 15;
  int t = threadIdx.x;
  {
    const float4* src = (const float4*)d2h + rt * 1024;
#pragma unroll
    for (int i = 0; i < 4; ++i) a_lds[i * 256 + t] = src[i * 256 + t];
  }
  __syncthreads();
  int lane = t & 63, w = t >> 6;
  int r0 = w * 2, r1 = w * 2 + 1;
  int p = pg * 64 + lane;
  const float4* wp0 = Wt4 + p;             // c=0
  const float4* wp1 = Wt4 + 131072 + p;    // c=1
  const float4* wp2 = Wt4 + 262144 + p;    // c=2
  float a00 = 0.f, a01 = 0.f, a02 = 0.f;
  float a10 = 0.f, a11 = 0.f, a12 = 0.f;
#pragma unroll 4
  for (int k4 = 0; k4 < 128; ++k4) {
    float4 A0 = a_lds[r0 * 128 + k4];      // wave-uniform broadcast
    float4 A1 = a_lds[r1 * 128 + k4];
    float4 w0 = wp0[k4 * 1024];
    float4 w1 = wp1[k4 * 1024];
    float4 w2 = wp2[k4 * 1024];
    a00 += A0.x * w0.x + A0.y * w0.y + A0.z * w0.z + A0.w * w0.w;
    a01 += A0.x * w1.x + A0.y * w1.y + A0.z * w1.z + A0.w * w1.w;
    a02 += A0.x * w2.x + A0.y * w2.y + A0.z * w2.z + A0.w * w2.w;
    a10 += A1.x * w0.x + A1.y * w0.y + A1.z * w0.z + A1.w * w0.w;
    a11 += A1.x * w1.x + A1.y * w1.y + A1.z * w1.z + A1.w * w1.w;
    a12 += A1.x * w2.x + A1.y * w2.y + A1.z * w2.z + A1.w * w2.w;
  }
  float b0 = bd3[p * 3], b1 = bd3[p * 3 + 1], b2 = bd3[p * 3 + 2];
  {
    int row = rt * 8 + r0;
    float y0 = tanhf(a00 + b0), y1 = tanhf(a01 + b1), y2 = tanhf(a02 + b2);
    Y4[row * 1024 + p] = make_float4(-2.f * y0, -2.f * y1, -2.f * y2,
                                     y0 * y0 + y1 * y1 + y2 * y2);
  }
  {
    int row = rt * 8 + r1;
    float y0 = tanhf(a10 + b0), y1 = tanhf(a11 + b1), y2 = tanhf(a12 + b2);
    Y4[row * 1024 + p] = make_float4(-2.f * y0, -2.f * y1, -2.f * y2,
                                     y0 * y0 + y1 * y1 + y2 * y2);
  }
}

// ---------------- K67: chamfer, 8 resident points/thread ----------------
// blocks 0..127: dir1 = (b, nt 0..31, mh 0..1): 2048 resident y, 512 s in LDS.
// blocks 128..255: dir2 = (b, nch 0..63): 1024 y in LDS, 8 s/thread,
//   half-block h covers 512 of the chunk's n.
__global__ __launch_bounds__(256) void k67_chamfer(
    const float4* __restrict__ Y4, const float4* __restrict__ S4,
    float* __restrict__ mp1, float* __restrict__ mp2) {
  int t = threadIdx.x;
  if (blockIdx.x < 128) {
    // ---- dir1 ----
    int b  = blockIdx.x >> 6;
    int nt = (blockIdx.x >> 1) & 31;
    int mh = blockIdx.x & 1;
    __shared__ float4 s_lds[512];          // 8 KB
    {
      const float4* src = S4 + b * 1024 + mh * 512;
      s_lds[t] = src[t];
      s_lds[256 + t] = src[256 + t];
    }
    const float4* yp = Y4 + b * 65536 + nt * 2048;
    float4 y0 = yp[0 * 256 + t], y1 = yp[1 * 256 + t];
    float4 y2 = yp[2 * 256 + t], y3 = yp[3 * 256 + t];
    float4 y4 = yp[4 * 256 + t], y5 = yp[5 * 256 + t];
    float4 y6 = yp[6 * 256 + t], y7 = yp[7 * 256 + t];
    __syncthreads();
    float mn0 = __builtin_inff(), mn1 = mn0, mn2 = mn0, mn3 = mn0;
    float mn4 = mn0, mn5 = mn0, mn6 = mn0, mn7 = mn0;
#pragma unroll 4
    for (int m = 0; m < 512; ++m) {
      float4 s = s_lds[m];                 // block-uniform broadcast
      mn0 = fminf(mn0, __builtin_fmaf(s.x, y0.x, __builtin_fmaf(s.y, y0.y, __builtin_fmaf(s.z, y0.z, s.w))));
      mn1 = fminf(mn1, __builtin_fmaf(s.x, y1.x, __builtin_fmaf(s.y, y1.y, __builtin_fmaf(s.z, y1.z, s.w))));
      mn2 = fminf(mn2, __builtin_fmaf(s.x, y2.x, __builtin_fmaf(s.y, y2.y, __builtin_fmaf(s.z, y2.z, s.w))));
      mn3 = fminf(mn3, __builtin_fmaf(s.x, y3.x, __builtin_fmaf(s.y, y3.y, __builtin_fmaf(s.z, y3.z, s.w))));
      mn4 = fminf(mn4, __builtin_fmaf(s.x, y4.x, __builtin_fmaf(s.y, y4.y, __builtin_fmaf(s.z, y4.z, s.w))));
      mn5 = fminf(mn5, __builtin_fmaf(s.x, y5.x, __builtin_fmaf(s.y, y5.y, __builtin_fmaf(s.z, y5.z, s.w))));
      mn6 = fminf(mn6, __builtin_fmaf(s.x, y6.x, __builtin_fmaf(s.y, y6.y, __builtin_fmaf(s.z, y6.z, s.w))));
      mn7 = fminf(mn7, __builtin_fmaf(s.x, y7.x, __builtin_fmaf(s.y, y7.y, __builtin_fmaf(s.z, y7.z, s.w))));
    }
    float* dst = mp1 + (b * 2 + mh) * 65536 + nt * 2048;
    dst[0 * 256 + t] = mn0 + y0.w;
    dst[1 * 256 + t] = mn1 + y1.w;
    dst[2 * 256 + t] = mn2 + y2.w;
    dst[3 * 256 + t] = mn3 + y3.w;
    dst[4 * 256 + t] = mn4 + y4.w;
    dst[5 * 256 + t] = mn5 + y5.w;
    dst[6 * 256 + t] = mn6 + y6.w;
    dst[7 * 256 + t] = mn7 + y7.w;
  } else {
    // ---- dir2 ----
    int blk = blockIdx.x - 128;
    int b = blk >> 6, nch = blk & 63;
    __shared__ float4 y_lds[1024];         // 16 KB
    {
      const float4* src = Y4 + b * 65536 + nch * 1024;
#pragma unroll
      for (int i = 0; i < 4; ++i) y_lds[i * 256 + t] = src[i * 256 + t];
    }
    int h = t >> 7, tm = t & 127;
    const float4* sp = S4 + b * 1024;
    float4 s0 = sp[0 * 128 + tm], s1 = sp[1 * 128 + tm];
    float4 s2 = sp[2 * 128 + tm], s3 = sp[3 * 128 + tm];
    float4 s4 = sp[4 * 128 + tm], s5 = sp[5 * 128 + tm];
    float4 s6 = sp[6 * 128 + tm], s7 = sp[7 * 128 + tm];
    __syncthreads();
    float mn0 = __builtin_inff(), mn1 = mn0, mn2 = mn0, mn3 = mn0;
    float mn4 = mn0, mn5 = mn0, mn6 = mn0, mn7 = mn0;
    const float4* yq = y_lds + h * 512;
#pragma unroll 4
    for (int nn = 0; nn < 512; ++nn) {
      float4 y = yq[nn];                   // wave-uniform broadcast
      mn0 = fminf(mn0, __builtin_fmaf(y.x, s0.x, __builtin_fmaf(y.y, s0.y, __builtin_fmaf(y.z, s0.z, y.w))));
      mn1 = fminf(mn1, __builtin_fmaf(y.x, s1.x, __builtin_fmaf(y.y, s1.y, __builtin_fmaf(y.z, s1.z, y.w))));
      mn2 = fminf(mn2, __builtin_fmaf(y.x, s2.x, __builtin_fmaf(y.y, s2.y, __builtin_fmaf(y.z, s2.z, y.w))));
      mn3 = fminf(mn3, __builtin_fmaf(y.x, s3.x, __builtin_fmaf(y.y, s3.y, __builtin_fmaf(y.z, s3.z, y.w))));
      mn4 = fminf(mn4, __builtin_fmaf(y.x, s4.x, __builtin_fmaf(y.y, s4.y, __builtin_fmaf(y.z, s4.z, y.w))));
      mn5 = fminf(mn5, __builtin_fmaf(y.x, s5.x, __builtin_fmaf(y.y, s5.y, __builtin_fmaf(y.z, s5.z, y.w))));
      mn6 = fminf(mn6, __builtin_fmaf(y.x, s6.x, __builtin_fmaf(y.y, s6.y, __builtin_fmaf(y.z, s6.z, y.w))));
      mn7 = fminf(mn7, __builtin_fmaf(y.x, s7.x, __builtin_fmaf(y.y, s7.y, __builtin_fmaf(y.z, s7.z, y.w))));
    }
    float* dst = mp2 + ((b * 64 + nch) * 2 + h) * 1024;
    dst[0 * 128 + tm] = mn0 + s0.w;
    dst[1 * 128 + tm] = mn1 + s1.w;
    dst[2 * 128 + tm] = mn2 + s2.w;
    dst[3 * 128 + tm] = mn3 + s3.w;
    dst[4 * 128 + tm] = mn4 + s4.w;
    dst[5 * 128 + tm] = mn5 + s5.w;
    dst[6 * 128 + tm] = mn6 + s6.w;
    dst[7 * 128 + tm] = mn7 + s7.w;
  }
}

// ---------------- K8: final reduce (both directions) ----------------
// blocks 0..63: dir1 (min over 2 m-halves, sum). blocks 64..71: dir2
// (min over 128 chunk-slots per (b,m), sum). One atomicAdd per block.
__global__ __launch_bounds__(256) void k8_reduce(
    const float* __restrict__ mp1, const float* __restrict__ mp2,
    float* __restrict__ out) {
  int t = threadIdx.x;
  float v = 0.f;
  if (blockIdx.x < 64) {
    int base = blockIdx.x * 2048;
#pragma unroll
    for (int i = 0; i < 8; ++i) {
      int n = base + i * 256 + t;          // 0..131071 = b*65536 + nn
      int b = n >> 16, nn = n & 65535;
      v += fminf(mp1[b * 131072 + nn], mp1[b * 131072 + 65536 + nn]);
    }
  } else {
    int gid = (blockIdx.x - 64) * 256 + t; // 0..2047 = (b, m)
    int b = gid >> 10, m = gid & 1023;
    float mv = __builtin_inff();
#pragma unroll 8
    for (int ch = 0; ch < 128; ++ch)
      mv = fminf(mv, mp2[(b * 128 + ch) * 1024 + m]);  // coalesced over m
    v = mv;
  }
#pragma unroll
  for (int off = 32; off > 0; off >>= 1) v += __shfl_down(v, off);
  __shared__ float bsum[4];
  int lane = t & 63, w = t >> 6;
  if (lane == 0) bsum[w] = v;
  __syncthreads();
  if (t == 0) atomicAdd(out, bsum[0] + bsum[1] + bsum[2] + bsum[3]);
}

extern "C" void kernel_launch(void* const* d_in, const int* in_sizes, int n_in,
                              void* d_out, int out_size, void* d_ws, size_t ws_size,
                              hipStream_t stream) {
  const float* x   = (const float*)d_in[0];
  const float* grd = (const float*)d_in[1];
  const float* We1 = (const float*)d_in[2];
  const float* be1 = (const float*)d_in[3];
  const float* We2 = (const float*)d_in[4];
  const float* be2 = (const float*)d_in[5];
  const float* We3 = (const float*)d_in[6];
  const float* be3 = (const float*)d_in[7];
  const float* Wd1 = (const float*)d_in[8];
  const float* bd1 = (const float*)d_in[9];
  const float* Wd2 = (const float*)d_in[10];
  const float* bd2 = (const float*)d_in[11];
  const float* Wd3 = (const float*)d_in[12];
  const float* bd3 = (const float*)d_in[13];
  float* ws = (float*)d_ws;
  float* out = (float*)d_out;

  float* h1pre = ws + OFF_H1PRE;
  float* zw    = ws + OFF_ZW;
  float* gw    = ws + OFF_GW;
  float* d2h   = ws + OFF_D2H;
  float* S4    = ws + OFF_S4;
  float* Y4    = ws + OFF_Y4;
  float4* Wt4  = (float4*)(ws + OFF_WT4);
  float* mp1   = ws + OFF_MP1;
  float* mp2   = ws + OFF_MP2;

  hipLaunchKernelGGL(k0_init_t, dim3(1600), dim3(256), 0, stream,
                     x, grd, Wd1, Wd3, gw, S4, Wt4, h1pre, out);
  hipLaunchKernelGGL(k1_enc1, dim3(192), dim3(128), 0, stream, x, We1, h1pre);
  hipLaunchKernelGGL(k23_enc, dim3(1), dim3(256), 0, stream,
                     h1pre, be1, We2, be2, We3, be3, Wd1, bd1, zw);
  hipLaunchKernelGGL(k4_dec2, dim3(128), dim3(256), 0, stream,
                     zw, gw, Wd2, bd2, d2h);
  hipLaunchKernelGGL(k5_dec3_y4, dim3(256), dim3(256), 0, stream,
                     d2h, Wt4, bd3, (float4*)Y4);
  hipLaunchKernelGGL(k67_chamfer, dim3(256), dim3(256), 0, stream,
                     (const float4*)Y4, (const float4*)S4, mp1, mp2);
  hipLaunchKernelGGL(k8_reduce, dim3(72), dim3(256), 0, stream,
                     mp1, mp2, out);
}

// Round 6
// 201.627 us; speedup vs baseline: 1.8887x; 1.1965x over previous
//
#include <hip/hip_runtime.h>

// Problem constants
#define NB 2        // batch
#define NPTS 1024   // points per cloud
#define NGEN 65536  // G * D_IN generated points per batch

// ws layout (float offsets), all 16B-aligned where accessed as float4.
#define OFF_GW    0        // 8192
#define OFF_ZW    8192     // 256
#define OFF_H1P   8448     // 24576 (L1 partials [kc24][b][512])
#define OFF_H2P   33024    // 2048  (L2 partials [kc8][b][128])
#define OFF_D2H   35072    // 65536
#define OFF_S4    100608   // 8192
#define OFF_Y4    108800   // 524288
#define OFF_WT4   633088   // 1572864 (3*128*1024 float4)
#define OFF_MP1   2205952  // 262144 (dir1 partial mins: [b][mh][65536])
#define OFF_MP2   2468096  // 262144 (dir2 partial mins: [b][nch][h][1024])
// total 2730240 floats = 10.9 MB

// ---------------- KA: init + S4 + gw + Wd3 transpose + enc-L1 partials -----
// blocks 0..63: init; 64..1599: transpose Wd3 -> Wt4[c][k4][p];
// 1600..1695: L1 partials (96 blocks = b(2) x jb(2) x kc(24)), no atomics.
__global__ __launch_bounds__(256) void kA_front(
    const float* __restrict__ x, const float* __restrict__ grid,
    const float* __restrict__ Wd1, const float* __restrict__ Wd3,
    const float* __restrict__ We1,
    float* __restrict__ gw, float* __restrict__ S4,
    float4* __restrict__ Wt4, float* __restrict__ h1part,
    float* __restrict__ out) {
  int blk = blockIdx.x;
  if (blk < 64) {
    int t = blk * 256 + threadIdx.x;
    if (t < 8192) {
      int g = t >> 7, j = t & 127;
      float a = grid[g * 3 + 0] * Wd1[64 * 128 + j]
              + grid[g * 3 + 1] * Wd1[65 * 128 + j]
              + grid[g * 3 + 2] * Wd1[66 * 128 + j];
      gw[t] = a;
    } else if (t < 10240) {
      int p = t - 8192;
      const float* xp = x + p * 3;
      float s0 = xp[0], s1 = xp[1], s2 = xp[2];
      ((float4*)S4)[p] = make_float4(s0, s1, s2, s0 * s0 + s1 * s1 + s2 * s2);
    } else if (t == 10240) {
      out[0] = 0.f;
    }
  } else if (blk < 1600) {
    int tid = (blk - 64) * 256 + threadIdx.x;         // 0..393215
    int p  = tid & 1023;
    int k4 = (tid >> 10) & 127;
    int c  = tid >> 17;                               // 0..2
    const float* W = Wd3 + (k4 * 4) * 3072 + p * 3 + c;
    float w0 = W[0], w1 = W[3072], w2 = W[2 * 3072], w3 = W[3 * 3072];
    Wt4[(c * 128 + k4) * 1024 + p] = make_float4(w0, w1, w2, w3);
  } else {
    // L1 partials: idx = 0..95; kc=idx%24, jb=(idx/24)&1, b=idx/48
    int idx = blk - 1600;
    int kc = idx % 24;
    int jb = (idx / 24) & 1;
    int b  = idx / 48;
    int j = jb * 256 + threadIdx.x;                   // 0..511
    const float* xb = x + b * 3072 + kc * 128;        // uniform -> s_load
    const float* W  = We1 + (kc * 128) * 512 + j;
    float acc = 0.f;
#pragma unroll 8
    for (int k = 0; k < 128; ++k) acc += xb[k] * W[k * 512];
    h1part[(kc * 2 + b) * 512 + j] = acc;             // no atomics
  }
}

// ---------------- KB: reduce L1 partials + enc L2 partials ----------------
// 16 blocks = b(2) x kc2(8); 128 threads. Block covers k-slice of 64.
__global__ __launch_bounds__(128) void kB_enc2(
    const float* __restrict__ h1part, const float* __restrict__ be1,
    const float* __restrict__ We2, float* __restrict__ h2part) {
  __shared__ float h1s[64];
  int b = blockIdx.x >> 3, kc2 = blockIdx.x & 7;
  int t = threadIdx.x;
  if (t < 64) {
    int k = kc2 * 64 + t;
    float acc = be1[k];
#pragma unroll
    for (int p = 0; p < 24; ++p) acc += h1part[(p * 2 + b) * 512 + k];
    h1s[t] = fmaxf(acc, 0.f);
  }
  __syncthreads();
  float acc = 0.f;
#pragma unroll 8
  for (int kk = 0; kk < 64; ++kk) {
    int k = kc2 * 64 + kk;
    acc += h1s[kk] * We2[k * 128 + t];
  }
  h2part[(kc2 * 2 + b) * 128 + t] = acc;              // bias added in kC
}

// ---------------- KC: reduce L2 + L3 + zw (weights staged in LDS) ---------
// 1 block, 256 threads.
__global__ __launch_bounds__(256) void kC_enc3_zw(
    const float* __restrict__ h2part, const float* __restrict__ be2,
    const float* __restrict__ We3, const float* __restrict__ be3,
    const float* __restrict__ Wd1, const float* __restrict__ bd1,
    float* __restrict__ zw) {
  __shared__ float h2s[256];
  __shared__ float zs[128];
  __shared__ float We3s[8192];             // 32 KB
  __shared__ float Wd1s[8192];             // 32 KB (first 64 rows of Wd1)
  int t = threadIdx.x;
  {
    int b = t >> 7, j = t & 127;
    float acc = be2[j];
#pragma unroll
    for (int p = 0; p < 8; ++p) acc += h2part[(p * 2 + b) * 128 + j];
    h2s[t] = fmaxf(acc, 0.f);
  }
  {
    const float4* src3 = (const float4*)We3;
    const float4* src1 = (const float4*)Wd1;
    float4* d3 = (float4*)We3s;
    float4* d1 = (float4*)Wd1s;
#pragma unroll
    for (int i = 0; i < 8; ++i) {
      d3[i * 256 + t] = src3[i * 256 + t];
      d1[i * 256 + t] = src1[i * 256 + t];
    }
  }
  __syncthreads();
  if (t < 128) {
    int b = t >> 6, j = t & 63;
    float acc = be3[j];
#pragma unroll 8
    for (int k = 0; k < 128; ++k) acc += h2s[b * 128 + k] * We3s[k * 64 + j];
    zs[t] = fmaxf(acc, 0.f);
  }
  __syncthreads();
  {
    int b = t >> 7, jj = t & 127;
    float a2 = bd1[jj];
#pragma unroll 8
    for (int k = 0; k < 64; ++k) a2 += zs[b * 64 + k] * Wd1s[k * 128 + jj];
    zw[t] = a2;                          // relu applied with gw in kD
  }
}

// ---------------- KD: decoder L2 ----------------
__global__ __launch_bounds__(256) void kD_dec2(
    const float* __restrict__ zw, const float* __restrict__ gw,
    const float* __restrict__ Wd2, const float* __restrict__ bd2,
    float* __restrict__ d2h) {
  __shared__ float d1[128];
  int bg = blockIdx.x;
  int b = bg >> 6, g = bg & 63;
  int t = threadIdx.x;
  if (t < 128) d1[t] = fmaxf(zw[b * 128 + t] + gw[g * 128 + t], 0.f);
  __syncthreads();
  float a0 = bd2[t], a1 = bd2[t + 256];
#pragma unroll 4
  for (int k = 0; k < 128; ++k) {
    float dv = d1[k];
    a0 += dv * Wd2[k * 512 + t];
    a1 += dv * Wd2[k * 512 + t + 256];
  }
  float* o = d2h + bg * 512;
  o[t] = fmaxf(a0, 0.f);
  o[t + 256] = fmaxf(a1, 0.f);
}

// ---------------- KE: decoder L3 + tanh + (-2y, |y|^2) pack ----------------
// 256 blocks = rt(16 row-tiles of 8) x pg(16); 256 threads (4 waves).
__global__ __launch_bounds__(256) void kE_dec3_y4(
    const float* __restrict__ d2h, const float4* __restrict__ Wt4,
    const float* __restrict__ bd3, float4* __restrict__ Y4) {
  __shared__ float4 a_lds[8 * 128];        // 8 rows x 512 k = 16 KB
  int rt = blockIdx.x >> 4;
  int pg = blockIdx.x & 15;
  int t = threadIdx.x;
  {
    const float4* src = (const float4*)d2h + rt * 1024;
#pragma unroll
    for (int i = 0; i < 4; ++i) a_lds[i * 256 + t] = src[i * 256 + t];
  }
  __syncthreads();
  int lane = t & 63, w = t >> 6;
  int r0 = w * 2, r1 = w * 2 + 1;
  int p = pg * 64 + lane;
  const float4* wp0 = Wt4 + p;             // c=0
  const float4* wp1 = Wt4 + 131072 + p;    // c=1
  const float4* wp2 = Wt4 + 262144 + p;    // c=2
  float a00 = 0.f, a01 = 0.f, a02 = 0.f;
  float a10 = 0.f, a11 = 0.f, a12 = 0.f;
#pragma unroll 4
  for (int k4 = 0; k4 < 128; ++k4) {
    float4 A0 = a_lds[r0 * 128 + k4];      // wave-uniform broadcast
    float4 A1 = a_lds[r1 * 128 + k4];
    float4 w0 = wp0[k4 * 1024];
    float4 w1 = wp1[k4 * 1024];
    float4 w2 = wp2[k4 * 1024];
    a00 += A0.x * w0.x + A0.y * w0.y + A0.z * w0.z + A0.w * w0.w;
    a01 += A0.x * w1.x + A0.y * w1.y + A0.z * w1.z + A0.w * w1.w;
    a02 += A0.x * w2.x + A0.y * w2.y + A0.z * w2.z + A0.w * w2.w;
    a10 += A1.x * w0.x + A1.y * w0.y + A1.z * w0.z + A1.w * w0.w;
    a11 += A1.x * w1.x + A1.y * w1.y + A1.z * w1.z + A1.w * w1.w;
    a12 += A1.x * w2.x + A1.y * w2.y + A1.z * w2.z + A1.w * w2.w;
  }
  float b0 = bd3[p * 3], b1 = bd3[p * 3 + 1], b2 = bd3[p * 3 + 2];
  {
    int row = rt * 8 + r0;
    float y0 = tanhf(a00 + b0), y1 = tanhf(a01 + b1), y2 = tanhf(a02 + b2);
    Y4[row * 1024 + p] = make_float4(-2.f * y0, -2.f * y1, -2.f * y2,
                                     y0 * y0 + y1 * y1 + y2 * y2);
  }
  {
    int row = rt * 8 + r1;
    float y0 = tanhf(a10 + b0), y1 = tanhf(a11 + b1), y2 = tanhf(a12 + b2);
    Y4[row * 1024 + p] = make_float4(-2.f * y0, -2.f * y1, -2.f * y2,
                                     y0 * y0 + y1 * y1 + y2 * y2);
  }
}

// ---------------- KF: chamfer, 8 resident points/thread ----------------
// blocks 0..127: dir1 = (b, nt 0..31, mh 0..1): 2048 resident y, 512 s in LDS.
// blocks 128..255: dir2 = (b, nch 0..63): 1024 y in LDS, 8 s/thread,
//   half-block h covers 512 of the chunk's n.
__global__ __launch_bounds__(256) void kF_chamfer(
    const float4* __restrict__ Y4, const float4* __restrict__ S4,
    float* __restrict__ mp1, float* __restrict__ mp2) {
  int t = threadIdx.x;
  if (blockIdx.x < 128) {
    // ---- dir1 ----
    int b  = blockIdx.x >> 6;
    int nt = (blockIdx.x >> 1) & 31;
    int mh = blockIdx.x & 1;
    __shared__ float4 s_lds[512];          // 8 KB
    {
      const float4* src = S4 + b * 1024 + mh * 512;
      s_lds[t] = src[t];
      s_lds[256 + t] = src[256 + t];
    }
    const float4* yp = Y4 + b * 65536 + nt * 2048;
    float4 y0 = yp[0 * 256 + t], y1 = yp[1 * 256 + t];
    float4 y2 = yp[2 * 256 + t], y3 = yp[3 * 256 + t];
    float4 y4 = yp[4 * 256 + t], y5 = yp[5 * 256 + t];
    float4 y6 = yp[6 * 256 + t], y7 = yp[7 * 256 + t];
    __syncthreads();
    float mn0 = __builtin_inff(), mn1 = mn0, mn2 = mn0, mn3 = mn0;
    float mn4 = mn0, mn5 = mn0, mn6 = mn0, mn7 = mn0;
#pragma unroll 4
    for (int m = 0; m < 512; ++m) {
      float4 s = s_lds[m];                 // block-uniform broadcast
      mn0 = fminf(mn0, __builtin_fmaf(s.x, y0.x, __builtin_fmaf(s.y, y0.y, __builtin_fmaf(s.z, y0.z, s.w))));
      mn1 = fminf(mn1, __builtin_fmaf(s.x, y1.x, __builtin_fmaf(s.y, y1.y, __builtin_fmaf(s.z, y1.z, s.w))));
      mn2 = fminf(mn2, __builtin_fmaf(s.x, y2.x, __builtin_fmaf(s.y, y2.y, __builtin_fmaf(s.z, y2.z, s.w))));
      mn3 = fminf(mn3, __builtin_fmaf(s.x, y3.x, __builtin_fmaf(s.y, y3.y, __builtin_fmaf(s.z, y3.z, s.w))));
      mn4 = fminf(mn4, __builtin_fmaf(s.x, y4.x, __builtin_fmaf(s.y, y4.y, __builtin_fmaf(s.z, y4.z, s.w))));
      mn5 = fminf(mn5, __builtin_fmaf(s.x, y5.x, __builtin_fmaf(s.y, y5.y, __builtin_fmaf(s.z, y5.z, s.w))));
      mn6 = fminf(mn6, __builtin_fmaf(s.x, y6.x, __builtin_fmaf(s.y, y6.y, __builtin_fmaf(s.z, y6.z, s.w))));
      mn7 = fminf(mn7, __builtin_fmaf(s.x, y7.x, __builtin_fmaf(s.y, y7.y, __builtin_fmaf(s.z, y7.z, s.w))));
    }
    float* dst = mp1 + (b * 2 + mh) * 65536 + nt * 2048;
    dst[0 * 256 + t] = mn0 + y0.w;
    dst[1 * 256 + t] = mn1 + y1.w;
    dst[2 * 256 + t] = mn2 + y2.w;
    dst[3 * 256 + t] = mn3 + y3.w;
    dst[4 * 256 + t] = mn4 + y4.w;
    dst[5 * 256 + t] = mn5 + y5.w;
    dst[6 * 256 + t] = mn6 + y6.w;
    dst[7 * 256 + t] = mn7 + y7.w;
  } else {
    // ---- dir2 ----
    int blk = blockIdx.x - 128;
    int b = blk >> 6, nch = blk & 63;
    __shared__ float4 y_lds[1024];         // 16 KB
    {
      const float4* src = Y4 + b * 65536 + nch * 1024;
#pragma unroll
      for (int i = 0; i < 4; ++i) y_lds[i * 256 + t] = src[i * 256 + t];
    }
    int h = t >> 7, tm = t & 127;
    const float4* sp = S4 + b * 1024;
    float4 s0 = sp[0 * 128 + tm], s1 = sp[1 * 128 + tm];
    float4 s2 = sp[2 * 128 + tm], s3 = sp[3 * 128 + tm];
    float4 s4 = sp[4 * 128 + tm], s5 = sp[5 * 128 + tm];
    float4 s6 = sp[6 * 128 + tm], s7 = sp[7 * 128 + tm];
    __syncthreads();
    float mn0 = __builtin_inff(), mn1 = mn0, mn2 = mn0, mn3 = mn0;
    float mn4 = mn0, mn5 = mn0, mn6 = mn0, mn7 = mn0;
    const float4* yq = y_lds + h * 512;
#pragma unroll 4
    for (int nn = 0; nn < 512; ++nn) {
      float4 y = yq[nn];                   // wave-uniform broadcast
      mn0 = fminf(mn0, __builtin_fmaf(y.x, s0.x, __builtin_fmaf(y.y, s0.y, __builtin_fmaf(y.z, s0.z, y.w))));
      mn1 = fminf(mn1, __builtin_fmaf(y.x, s1.x, __builtin_fmaf(y.y, s1.y, __builtin_fmaf(y.z, s1.z, y.w))));
      mn2 = fminf(mn2, __builtin_fmaf(y.x, s2.x, __builtin_fmaf(y.y, s2.y, __builtin_fmaf(y.z, s2.z, y.w))));
      mn3 = fminf(mn3, __builtin_fmaf(y.x, s3.x, __builtin_fmaf(y.y, s3.y, __builtin_fmaf(y.z, s3.z, y.w))));
      mn4 = fminf(mn4, __builtin_fmaf(y.x, s4.x, __builtin_fmaf(y.y, s4.y, __builtin_fmaf(y.z, s4.z, y.w))));
      mn5 = fminf(mn5, __builtin_fmaf(y.x, s5.x, __builtin_fmaf(y.y, s5.y, __builtin_fmaf(y.z, s5.z, y.w))));
      mn6 = fminf(mn6, __builtin_fmaf(y.x, s6.x, __builtin_fmaf(y.y, s6.y, __builtin_fmaf(y.z, s6.z, y.w))));
      mn7 = fminf(mn7, __builtin_fmaf(y.x, s7.x, __builtin_fmaf(y.y, s7.y, __builtin_fmaf(y.z, s7.z, y.w))));
    }
    float* dst = mp2 + ((b * 64 + nch) * 2 + h) * 1024;
    dst[0 * 128 + tm] = mn0 + s0.w;
    dst[1 * 128 + tm] = mn1 + s1.w;
    dst[2 * 128 + tm] = mn2 + s2.w;
    dst[3 * 128 + tm] = mn3 + s3.w;
    dst[4 * 128 + tm] = mn4 + s4.w;
    dst[5 * 128 + tm] = mn5 + s5.w;
    dst[6 * 128 + tm] = mn6 + s6.w;
    dst[7 * 128 + tm] = mn7 + s7.w;
  }
}

// ---------------- KG: final reduce (both directions) ----------------
// blocks 0..63: dir1 (min over 2 m-halves, sum). blocks 64..71: dir2
// (min over 128 chunk-slots per (b,m), sum). One atomicAdd per block.
__global__ __launch_bounds__(256) void kG_reduce(
    const float* __restrict__ mp1, const float* __restrict__ mp2,
    float* __restrict__ out) {
  int t = threadIdx.x;
  float v = 0.f;
  if (blockIdx.x < 64) {
    int base = blockIdx.x * 2048;
#pragma unroll
    for (int i = 0; i < 8; ++i) {
      int n = base + i * 256 + t;          // 0..131071 = b*65536 + nn
      int b = n >> 16, nn = n & 65535;
      v += fminf(mp1[b * 131072 + nn], mp1[b * 131072 + 65536 + nn]);
    }
  } else {
    int gid = (blockIdx.x - 64) * 256 + t; // 0..2047 = (b, m)
    int b = gid >> 10, m = gid & 1023;
    float mv = __builtin_inff();
#pragma unroll 8
    for (int ch = 0; ch < 128; ++ch)
      mv = fminf(mv, mp2[(b * 128 + ch) * 1024 + m]);  // coalesced over m
    v = mv;
  }
#pragma unroll
  for (int off = 32; off > 0; off >>= 1) v += __shfl_down(v, off);
  __shared__ float bsum[4];
  int lane = t & 63, w = t >> 6;
  if (lane == 0) bsum[w] = v;
  __syncthreads();
  if (t == 0) atomicAdd(out, bsum[0] + bsum[1] + bsum[2] + bsum[3]);
}

extern "C" void kernel_launch(void* const* d_in, const int* in_sizes, int n_in,
                              void* d_out, int out_size, void* d_ws, size_t ws_size,
                              hipStream_t stream) {
  const float* x   = (const float*)d_in[0];
  const float* grd = (const float*)d_in[1];
  const float* We1 = (const float*)d_in[2];
  const float* be1 = (const float*)d_in[3];
  const float* We2 = (const float*)d_in[4];
  const float* be2 = (const float*)d_in[5];
  const float* We3 = (const float*)d_in[6];
  const float* be3 = (const float*)d_in[7];
  const float* Wd1 = (const float*)d_in[8];
  const float* bd1 = (const float*)d_in[9];
  const float* Wd2 = (const float*)d_in[10];
  const float* bd2 = (const float*)d_in[11];
  const float* Wd3 = (const float*)d_in[12];
  const float* bd3 = (const float*)d_in[13];
  float* ws = (float*)d_ws;
  float* out = (float*)d_out;

  float* gw     = ws + OFF_GW;
  float* zw     = ws + OFF_ZW;
  float* h1part = ws + OFF_H1P;
  float* h2part = ws + OFF_H2P;
  float* d2h    = ws + OFF_D2H;
  float* S4     = ws + OFF_S4;
  float* Y4     = ws + OFF_Y4;
  float4* Wt4   = (float4*)(ws + OFF_WT4);
  float* mp1    = ws + OFF_MP1;
  float* mp2    = ws + OFF_MP2;

  hipLaunchKernelGGL(kA_front, dim3(1696), dim3(256), 0, stream,
                     x, grd, Wd1, Wd3, We1, gw, S4, Wt4, h1part, out);
  hipLaunchKernelGGL(kB_enc2, dim3(16), dim3(128), 0, stream,
                     h1part, be1, We2, h2part);
  hipLaunchKernelGGL(kC_enc3_zw, dim3(1), dim3(256), 0, stream,
                     h2part, be2, We3, be3, Wd1, bd1, zw);
  hipLaunchKernelGGL(kD_dec2, dim3(128), dim3(256), 0, stream,
                     zw, gw, Wd2, bd2, d2h);
  hipLaunchKernelGGL(kE_dec3_y4, dim3(256), dim3(256), 0, stream,
                     d2h, Wt4, bd3, (float4*)Y4);
  hipLaunchKernelGGL(kF_chamfer, dim3(256), dim3(256), 0, stream,
                     (const float4*)Y4, (const float4*)S4, mp1, mp2);
  hipLaunchKernelGGL(kG_reduce, dim3(72), dim3(256), 0, stream,
                     mp1, mp2, out);
}